// Round 3
// baseline (941.058 us; speedup 1.0000x reference)
//
#include <hip/hip_runtime.h>

// ---------------- ws float layout ----------------
#define F_S0    0      // 64: per-row scale for W0
#define F_WQ1   64     // 4096: fp32 quantized W1 [64][64]
#define F_WQ2   4160   // 4096: fp32 quantized W2 [64][64]
#define F_WQ3   8256   // 640 : fp32 quantized W3 [10][64]
#define F_BN0   8896   // g[64] be[64] m[64] r[64]
#define F_BN1   9152
#define F_BN2   9408
#define F_BN3   9664   // g[16] be[16] m[16] r[16] (10 used)

struct InPtrs { const float* p[25]; };

// ---------------- prep: fp32 scales/weights/BN consts (np-f32 exact ops) ----------------
__global__ __launch_bounds__(256) void qtfc_prep(InPtrs P, float* __restrict__ wsf) {
#pragma clang fp contract(off)
  __shared__ float red[256];
  const int tid = threadIdx.x, b = blockIdx.x;
  if (b < 64) {
    const int row = b;
    const float* W = P.p[1];
    float mx = 0.f;
    for (int k = tid; k < 3072; k += 256) mx = fmaxf(mx, fabsf(W[row * 3072 + k]));
    red[tid] = mx; __syncthreads();
    for (int s = 128; s > 0; s >>= 1) { if (tid < s) red[tid] = fmaxf(red[tid], red[tid + s]); __syncthreads(); }
    if (tid == 0) {
      wsf[F_S0 + row] = fmaxf(__fdiv_rn(red[0], 7.f), 1e-8f);
      const float g = P.p[3][row], be = P.p[4][row], m = P.p[5][row], v = P.p[6][row];
      const float r = __fdiv_rn(1.f, __fsqrt_rn(__fadd_rn(v, 1e-5f)));
      wsf[F_BN0 + row] = g; wsf[F_BN0 + 64 + row] = be; wsf[F_BN0 + 128 + row] = m; wsf[F_BN0 + 192 + row] = r;
    }
  } else if (b < 192) {
    const int lay = b >> 6, row = b & 63;   // lay = 1,2
    const float* W = P.p[1 + 6 * lay];
    red[tid] = (tid < 64) ? fabsf(W[row * 64 + tid]) : 0.f; __syncthreads();
    for (int s = 128; s > 0; s >>= 1) { if (tid < s) red[tid] = fmaxf(red[tid], red[tid + s]); __syncthreads(); }
    const float sv = fmaxf(__fdiv_rn(red[0], 7.f), 1e-8f);
    float* wq = wsf + (lay == 1 ? F_WQ1 : F_WQ2);
    if (tid < 64)
      wq[row * 64 + tid] = __fmul_rn(rintf(__fdiv_rn(W[row * 64 + tid], sv)), sv);
    if (tid == 0) {
      const int base = (lay == 1) ? F_BN1 : F_BN2;
      const float g = P.p[3 + 6 * lay][row], be = P.p[4 + 6 * lay][row];
      const float m = P.p[5 + 6 * lay][row], v = P.p[6 + 6 * lay][row];
      const float r = __fdiv_rn(1.f, __fsqrt_rn(__fadd_rn(v, 1e-5f)));
      wsf[base + row] = g; wsf[base + 64 + row] = be; wsf[base + 128 + row] = m; wsf[base + 192 + row] = r;
    }
  } else {
    const float* W = P.p[19];
    float mx = 0.f;
    for (int k = tid; k < 640; k += 256) mx = fmaxf(mx, fabsf(W[k]));
    red[tid] = mx; __syncthreads();
    for (int s = 128; s > 0; s >>= 1) { if (tid < s) red[tid] = fmaxf(red[tid], red[tid + s]); __syncthreads(); }
    const float sv = fmaxf(__fdiv_rn(red[0], 7.f), 1e-8f);
    for (int k = tid; k < 640; k += 256)
      wsf[F_WQ3 + k] = __fmul_rn(rintf(__fdiv_rn(W[k], sv)), sv);
    if (tid < 10) {
      const float g = P.p[21][tid], be = P.p[22][tid], m = P.p[23][tid], v = P.p[24][tid];
      const float r = __fdiv_rn(1.f, __fsqrt_rn(__fadd_rn(v, 1e-5f)));
      wsf[F_BN3 + tid] = g; wsf[F_BN3 + 16 + tid] = be; wsf[F_BN3 + 32 + tid] = m; wsf[F_BN3 + 48 + tid] = r;
    }
  }
}

// ---------------- helpers (np-f32 exact) ----------------
__device__ __forceinline__ float qact8(float v) {
#pragma clang fp contract(off)
  const float y = fminf(fmaxf(v, -1.f), 1.f);
  return __fdiv_rn(rintf(__fmul_rn(y, 127.f)), 127.f);
}
__device__ __forceinline__ float bn_act4(float hv, float g, float be, float m, float r) {
#pragma clang fp contract(off)
  const float bnv = __fadd_rn(__fmul_rn(__fmul_rn(g, __fsub_rn(hv, m)), r), be);
  const float y = fminf(fmaxf(bnv, -1.f), 1.f);
  return __fdiv_rn(rintf(__fmul_rn(y, 7.f)), 7.f);
}

// one 64->64 fp32 layer: src/dst swizzled LDS tiles, w + bn from global
__device__ __forceinline__ void layer64(const float* __restrict__ src, float* __restrict__ dst,
                                        const float* __restrict__ wq, const float* __restrict__ bn,
                                        int rq, int cq) {
#pragma clang fp contract(off)
#pragma unroll
  for (int i = 0; i < 2; ++i) {
    const int row = rq * 2 + i, key = rq & 7;
    float4 av[16];
#pragma unroll
    for (int s = 0; s < 16; ++s) {
      const int sw = (s & 8) | ((s & 7) ^ key);
      av[s] = *(const float4*)(src + row * 64 + (sw << 2));
    }
#pragma unroll
    for (int j = 0; j < 8; ++j) {
      const int ch = cq * 8 + j;
      float a = 0.f;
#pragma unroll
      for (int s = 0; s < 16; ++s) {
        const float4 wv = *(const float4*)(wq + ch * 64 + s * 4);
        a = __fmaf_rn(av[s].x, wv.x, a);
        a = __fmaf_rn(av[s].y, wv.y, a);
        a = __fmaf_rn(av[s].z, wv.z, a);
        a = __fmaf_rn(av[s].w, wv.w, a);
      }
      const float af = bn_act4(a, bn[ch], bn[64 + ch], bn[128 + ch], bn[192 + ch]);
      const int slot = ch >> 2, sw = (slot & 8) | ((slot & 7) ^ key);
      dst[row * 64 + (sw << 2) + (ch & 3)] = af;
    }
  }
}

// ---------------- main fused kernel ----------------
__global__ __launch_bounds__(256) void qtfc_main(const float* __restrict__ x,
                                                 const float* __restrict__ W0,
                                                 const float* __restrict__ wsf,
                                                 float* __restrict__ out) {
#pragma clang fp contract(off)
  __shared__ float smem[8192];   // [0:2048) xt, [2048:4096) wt; later a2=smem[0:4096); a1=smem[4096:8192)
  __shared__ float sarr[64];
  const int tid = threadIdx.x;
  const int rq = tid >> 3, cq = tid & 7;
  const int row0 = blockIdx.x * 64;
  float* xt = smem; float* wt = smem + 2048;
  float* a2 = smem; float* a1 = smem + 4096;

  if (tid < 64) sarr[tid] = wsf[F_S0 + tid];
  __syncthreads();

  float acc[2][8], h[2][8];
#pragma unroll
  for (int i = 0; i < 2; ++i)
#pragma unroll
    for (int j = 0; j < 8; ++j) { acc[i][j] = 0.f; h[i][j] = 0.f; }

  // ---- layer 0: fp32 ascending-k fma chains, KC=384 block sums (OpenBLAS sgemm order) ----
  for (int t = 0; t < 96; ++t) {
    const long k0 = (long)t * 32;
    if (t) __syncthreads();
#pragma unroll
    for (int p = 0; p < 2; ++p) {
      const int u = tid + 256 * p;
      const int ur = u >> 3, us = u & 7;
      const float4 xv = *(const float4*)(x + (long)(row0 + ur) * 3072 + k0 + us * 4);
      float4 q;
      q.x = qact8(xv.x); q.y = qact8(xv.y); q.z = qact8(xv.z); q.w = qact8(xv.w);
      *(float4*)(xt + ur * 32 + ((us ^ ((ur >> 1) & 7)) << 2)) = q;
      const float4 wv = *(const float4*)(W0 + (long)ur * 3072 + k0 + us * 4);
      const float sv = sarr[ur];
      float4 wq;
      wq.x = __fmul_rn(rintf(__fdiv_rn(wv.x, sv)), sv);
      wq.y = __fmul_rn(rintf(__fdiv_rn(wv.y, sv)), sv);
      wq.z = __fmul_rn(rintf(__fdiv_rn(wv.z, sv)), sv);
      wq.w = __fmul_rn(rintf(__fdiv_rn(wv.w, sv)), sv);
      *(float4*)(wt + ur * 32 + ((us ^ ((ur >> 3) & 7)) << 2)) = wq;
    }
    __syncthreads();
#pragma unroll
    for (int s = 0; s < 8; ++s) {
      float4 xa[2], wb[8];
#pragma unroll
      for (int i = 0; i < 2; ++i) xa[i] = *(const float4*)(xt + (rq * 2 + i) * 32 + ((s ^ (rq & 7)) << 2));
#pragma unroll
      for (int j = 0; j < 8; ++j) wb[j] = *(const float4*)(wt + (cq * 8 + j) * 32 + ((s ^ cq) << 2));
#pragma unroll
      for (int i = 0; i < 2; ++i)
#pragma unroll
        for (int j = 0; j < 8; ++j) {
          acc[i][j] = __fmaf_rn(xa[i].x, wb[j].x, acc[i][j]);
          acc[i][j] = __fmaf_rn(xa[i].y, wb[j].y, acc[i][j]);
          acc[i][j] = __fmaf_rn(xa[i].z, wb[j].z, acc[i][j]);
          acc[i][j] = __fmaf_rn(xa[i].w, wb[j].w, acc[i][j]);
        }
    }
    if (((t + 1) % 12) == 0) {   // end of a 384-k block: C += block-chain (single fp32 add)
#pragma unroll
      for (int i = 0; i < 2; ++i)
#pragma unroll
        for (int j = 0; j < 8; ++j) { h[i][j] = __fadd_rn(h[i][j], acc[i][j]); acc[i][j] = 0.f; }
    }
  }

  // ---- layer 0 epilogue: BN + 4-bit act -> a1 ----
  {
    const float* bn0 = wsf + F_BN0;
#pragma unroll
    for (int i = 0; i < 2; ++i) {
      const int row = rq * 2 + i, key = rq & 7;
#pragma unroll
      for (int j = 0; j < 8; ++j) {
        const int ch = cq * 8 + j;
        const float af = bn_act4(h[i][j], bn0[ch], bn0[64 + ch], bn0[128 + ch], bn0[192 + ch]);
        const int slot = ch >> 2, sw = (slot & 8) | ((slot & 7) ^ key);
        a1[row * 64 + (sw << 2) + (ch & 3)] = af;
      }
    }
  }
  __syncthreads();

  // ---- layers 1,2 ----
  layer64(a1, a2, wsf + F_WQ1, wsf + F_BN1, rq, cq);
  __syncthreads();
  layer64(a2, a1, wsf + F_WQ2, wsf + F_BN2, rq, cq);
  __syncthreads();

  // ---- layer 3: 10 outputs, BN, no act ----
  {
    const float* wq3 = wsf + F_WQ3;
    const float* bn3 = wsf + F_BN3;
#pragma unroll
    for (int i = 0; i < 2; ++i) {
      const int row = rq * 2 + i, key = rq & 7;
      float4 av[16];
#pragma unroll
      for (int s = 0; s < 16; ++s) {
        const int sw = (s & 8) | ((s & 7) ^ key);
        av[s] = *(const float4*)(a1 + row * 64 + (sw << 2));
      }
#pragma unroll
      for (int j = 0; j < 8; ++j) {
        const int ch = cq * 8 + j;
        if (ch < 10) {
          float a = 0.f;
#pragma unroll
          for (int s = 0; s < 16; ++s) {
            const float4 wv = *(const float4*)(wq3 + ch * 64 + s * 4);
            a = __fmaf_rn(av[s].x, wv.x, a);
            a = __fmaf_rn(av[s].y, wv.y, a);
            a = __fmaf_rn(av[s].z, wv.z, a);
            a = __fmaf_rn(av[s].w, wv.w, a);
          }
          const float o = __fadd_rn(__fmul_rn(__fmul_rn(bn3[ch], __fsub_rn(a, bn3[32 + ch])), bn3[48 + ch]), bn3[16 + ch]);
          out[(long)(row0 + row) * 10 + ch] = o;
        }
      }
    }
  }
}

extern "C" void kernel_launch(void* const* d_in, const int* in_sizes, int n_in,
                              void* d_out, int out_size, void* d_ws, size_t ws_size,
                              hipStream_t stream) {
  (void)in_sizes; (void)n_in; (void)out_size; (void)ws_size;
  InPtrs P;
  for (int i = 0; i < 25; ++i) P.p[i] = (const float*)d_in[i];
  float* wsf = (float*)d_ws;
  qtfc_prep<<<193, 256, 0, stream>>>(P, wsf);
  qtfc_main<<<512, 256, 0, stream>>>((const float*)d_in[0], (const float*)d_in[1], wsf, (float*)d_out);
}